// Round 1
// baseline (217.785 us; speedup 1.0000x reference)
//
#include <hip/hip_runtime.h>

// DIN attention sequence pooling:
//   scores[b,t] = MLP(concat([q, k, q-k, q*k])) with sigmoid x2, masked by keys_length
//   out[b,:]    = sum_t scores[b,t] * keys[b,t,:]
// Algebra: att_in @ W1 = q@(W1a+W1c) + k@(W1b-W1c) + (q*k)@W1d
//        = [per-b constant qh] + k @ Wb,  Wb[e][h] = (W1b-W1c)[e][h] + q_e*W1d[e][h]
// One block per b. Keys staged transposed in LDS as bf16 (tolerance is bf16-scaled).

constexpr int Bn = 2048, Tn = 200, En = 64, H1n = 80, H2n = 40;
constexpr int KT_PAD = 210;   // bf16 row stride: 420B -> bank stride 9 (coprime 32), conflict-free both axes

__device__ __forceinline__ unsigned short f2bf(float x) {
  unsigned u = __float_as_uint(x);
  u += 0x7fffu + ((u >> 16) & 1u);   // RNE
  return (unsigned short)(u >> 16);
}
__device__ __forceinline__ float bf2f(unsigned short h) {
  return __uint_as_float(((unsigned)h) << 16);
}
__device__ __forceinline__ float fsig(float x) {
  return __fdividef(1.0f, 1.0f + __expf(-x));
}

__global__ __launch_bounds__(256) void din_attn_kernel(
    const float* __restrict__ query,
    const float* __restrict__ keys,
    const int*   __restrict__ keys_length,
    const float* __restrict__ W1, const float* __restrict__ b1,
    const float* __restrict__ W2, const float* __restrict__ b2,
    const float* __restrict__ W3, const float* __restrict__ b3,
    float* __restrict__ out)
{
  __shared__ unsigned short sKT[En][KT_PAD];  // keys^T, bf16: 26880 B
  __shared__ float sWb[En * H1n];             // folded layer-1 weights: 20480 B
  __shared__ float sQ[En];
  __shared__ float sQH[H1n];
  __shared__ float sS[256];
  __shared__ float sPool[4][En];

  const int b = blockIdx.x;
  const int tid = threadIdx.x;

  if (tid < En) sQ[tid] = query[(size_t)b * En + tid];
  __syncthreads();

  // ---- stage keys[b] -> LDS transposed bf16 (coalesced float4 global reads)
  {
    const float4* k4 = (const float4*)(keys + (size_t)b * Tn * En);
    for (int i = tid; i < Tn * En / 4; i += 256) {
      float4 v = k4[i];
      int base = i * 4;
      int t = base >> 6, e = base & 63;
      sKT[e + 0][t] = f2bf(v.x);
      sKT[e + 1][t] = f2bf(v.y);
      sKT[e + 2][t] = f2bf(v.z);
      sKT[e + 3][t] = f2bf(v.w);
    }
  }

  // ---- fold Wb[e][h] = (W1[64+e]-W1[128+e])[h] + q_e * W1[192+e][h]
  for (int i = tid; i < En * H1n; i += 256) {
    int e = i / H1n, h = i - e * H1n;
    float wk  = W1[(64 + e) * H1n + h] - W1[(128 + e) * H1n + h];
    float wqk = W1[(192 + e) * H1n + h];
    sWb[i] = wk + sQ[e] * wqk;
  }

  // ---- qh[h] = b1[h] + sum_e q_e*(W1[e][h] + W1[128+e][h])
  if (tid < H1n) {
    float a = b1[tid];
    for (int e = 0; e < En; ++e)
      a += sQ[e] * (W1[e * H1n + tid] + W1[(128 + e) * H1n + tid]);
    sQH[tid] = a;
  }
  __syncthreads();

  // ---- per-thread MLP over its sequence position t
  const int t = (tid < Tn) ? tid : 0;   // clamp: tail threads compute t=0, masked later

  float acc1[H1n];
  #pragma unroll
  for (int h = 0; h < H1n; ++h) acc1[h] = sQH[h];

  for (int e = 0; e < En; ++e) {
    float ke = bf2f(sKT[e][t]);
    const float4* w4 = (const float4*)(sWb + e * H1n);
    #pragma unroll
    for (int h4 = 0; h4 < H1n / 4; ++h4) {
      float4 w = w4[h4];
      acc1[h4 * 4 + 0] += ke * w.x;
      acc1[h4 * 4 + 1] += ke * w.y;
      acc1[h4 * 4 + 2] += ke * w.z;
      acc1[h4 * 4 + 3] += ke * w.w;
    }
  }
  #pragma unroll
  for (int h = 0; h < H1n; ++h) acc1[h] = fsig(acc1[h]);

  float acc2[H2n];
  #pragma unroll
  for (int j = 0; j < H2n; ++j) acc2[j] = b2[j];
  for (int h = 0; h < H1n; ++h) {
    float v = acc1[h];
    const float4* w4 = (const float4*)(W2 + h * H2n);
    #pragma unroll
    for (int j4 = 0; j4 < H2n / 4; ++j4) {
      float4 w = w4[j4];
      acc2[j4 * 4 + 0] += v * w.x;
      acc2[j4 * 4 + 1] += v * w.y;
      acc2[j4 * 4 + 2] += v * w.z;
      acc2[j4 * 4 + 3] += v * w.w;
    }
  }
  #pragma unroll
  for (int j = 0; j < H2n; ++j) acc2[j] = fsig(acc2[j]);

  float s = b3[0];
  #pragma unroll
  for (int j = 0; j < H2n; ++j) s += acc2[j] * W3[j];

  const int len = keys_length[b];
  sS[tid] = (tid < len) ? s : 0.0f;   // tid>=200 always masked (len<=200)
  __syncthreads();

  // ---- pooling: out[b][e] = sum_t s[t] * k[t][e]
  {
    int e = tid & 63, q = tid >> 6;
    float ps = 0.0f;
    int t0 = q * (Tn / 4);
    for (int t2 = t0; t2 < t0 + Tn / 4; ++t2)
      ps += sS[t2] * bf2f(sKT[e][t2]);
    sPool[q][e] = ps;
  }
  __syncthreads();
  if (tid < En) {
    out[(size_t)b * En + tid] =
        sPool[0][tid] + sPool[1][tid] + sPool[2][tid] + sPool[3][tid];
  }
}

extern "C" void kernel_launch(void* const* d_in, const int* in_sizes, int n_in,
                              void* d_out, int out_size, void* d_ws, size_t ws_size,
                              hipStream_t stream) {
  const float* query       = (const float*)d_in[0];
  const float* keys        = (const float*)d_in[1];
  const int*   keys_length = (const int*)d_in[2];
  const float* W1 = (const float*)d_in[3];
  const float* b1 = (const float*)d_in[4];
  const float* W2 = (const float*)d_in[5];
  const float* b2 = (const float*)d_in[6];
  const float* W3 = (const float*)d_in[7];
  const float* b3 = (const float*)d_in[8];
  float* out = (float*)d_out;

  hipLaunchKernelGGL(din_attn_kernel, dim3(Bn), dim3(256), 0, stream,
                     query, keys, keys_length, W1, b1, W2, b2, W3, b3, out);
}

// Round 3
// 130.892 us; speedup vs baseline: 1.6638x; 1.6638x over previous
//
#include <hip/hip_runtime.h>

// DIN attention pooling via MFMA (f16), one block per batch element b.
//   Wb[e][h] = (W1b - W1c)[e][h] + q_e * W1d[e][h]   (per-b folded layer-1 weight)
//   qh[h]    = b1[h] + sum_e q_e * (W1a + W1c)[e][h] (per-b layer-1 bias)
//   H = sigmoid(K @ Wb + qh); G = sigmoid(H @ W2 + b2); s = G @ W3 + b3 (masked)
//   out = s^T @ K
// All LDS matrices f16; MFMA 16x16x32_f16 (L1) and 16x16x16f16 (L2/L3).

constexpr int Bn = 2048, Tn = 200, En = 64, H1n = 80, H2n = 40;
constexpr int TP = 208;   // T padded to 13 m-tiles of 16
constexpr int MT = 13;

typedef _Float16 f16;
typedef _Float16 f16x8 __attribute__((ext_vector_type(8)));
typedef _Float16 f16x4 __attribute__((ext_vector_type(4)));
typedef float f32x4 __attribute__((ext_vector_type(4)));

// LDS row strides (f16 elements), chosen for uniform bank spread:
constexpr int SK_W  = 72;  // 144B: quad-slot = 9r+s mod 8 -> uniform for b128 frags
constexpr int SWB_W = 72;  // 144B
constexpr int SH_W  = 80;  // 160B: bank-pair = 20r+k8 mod 16 -> uniform for b64 frags
constexpr int SW2_W = 80;  // 160B
constexpr int SG_W  = 48;  // 96B:  pair = 12r+k8 mod 16 -> uniform

__device__ __forceinline__ float fsig(float x) {
  return __fdividef(1.0f, 1.0f + __expf(-x));
}

__global__ __launch_bounds__(256, 2) void din_attn_mfma(
    const float* __restrict__ query,
    const float* __restrict__ keys,
    const int*   __restrict__ keys_length,
    const float* __restrict__ W1, const float* __restrict__ b1,
    const float* __restrict__ W2, const float* __restrict__ b2,
    const float* __restrict__ W3, const float* __restrict__ b3,
    float* __restrict__ out)
{
  __shared__ __align__(16) f16 sK[TP * SK_W];                 // 29,952 B (live whole kernel)
  __shared__ __align__(16) unsigned char sU[TP * SH_W * 2];   // 33,280 B union region
  __shared__ __align__(16) f16 sW2T[48 * SW2_W];              // 7,680 B
  __shared__ __align__(16) f16 sW3T[48];                      // 96 B (single row, bcast cols)
  __shared__ float qh[H1n];
  __shared__ float sB2[48];
  __shared__ float sS[TP];
  __shared__ float sPool[4][En];

  f16* sWbT = (f16*)sU;   // [80][SWB_W]  phase 1
  f16* sH   = (f16*)sU;   // [TP][SH_W]   phase 2 (after barrier)
  f16* sG   = (f16*)sU;   // [TP][SG_W]   phase 3 (after barrier)

  const int b    = blockIdx.x;
  const int tid  = threadIdx.x;
  const int lane = tid & 63;
  const int wid  = tid >> 6;
  const int l15  = lane & 15;
  const int l4   = lane >> 4;

  const float* qptr = query + (size_t)b * En;

  // ---------------- P0: staging ----------------
  {
    const float4* k4 = (const float4*)(keys + (size_t)b * Tn * En);
    for (int i = tid; i < Tn * En / 4; i += 256) {
      float4 v = k4[i];
      int t = i >> 4, e4 = (i & 15) << 2;
      f16x4 h = { (f16)v.x, (f16)v.y, (f16)v.z, (f16)v.w };
      *(f16x4*)&sK[t * SK_W + e4] = h;
    }
    // zero-fill pad rows 200..207 (keep NaN/garbage out of MFMA)
    for (int i = tid; i < 8 * En / 4; i += 256) {
      int t = Tn + (i >> 4), e4 = (i & 15) << 2;
      *(f16x4*)&sK[t * SK_W + e4] = (f16x4){0, 0, 0, 0};
    }
  }
  // Wb^T[h][e] build (f16)
  for (int i = tid; i < 32 * H1n; i += 256) {
    int e2 = i & 31, h = i >> 5;
    int e = e2 << 1;
    float q0 = qptr[e], q1 = qptr[e + 1];
    float w0 = W1[(64 + e) * H1n + h] - W1[(128 + e) * H1n + h] + q0 * W1[(192 + e) * H1n + h];
    float w1 = W1[(65 + e) * H1n + h] - W1[(129 + e) * H1n + h] + q1 * W1[(193 + e) * H1n + h];
    sWbT[h * SWB_W + e]     = (f16)w0;
    sWbT[h * SWB_W + e + 1] = (f16)w1;
  }
  // W2^T[j][h], rows 40..47 zero (keeps G cols 40..47 finite: sigmoid(0)=0.5)
  for (int i = tid; i < 48 * H1n; i += 256) {
    int j = i % 48, h = i / 48;
    float w = (j < H2n) ? W2[h * H2n + j] : 0.0f;
    sW2T[j * SW2_W + h] = (f16)w;
  }
  // W3 row (k=40..47 zero so padded G cols contribute nothing)
  if (tid < 48) sW3T[tid] = (tid < H2n) ? (f16)W3[tid] : (f16)0.0f;
  // qh
  if (tid < H1n) {
    float a = b1[tid];
    for (int e = 0; e < En; ++e)
      a += qptr[e] * (W1[e * H1n + tid] + W1[(128 + e) * H1n + tid]);
    qh[tid] = a;
  }
  if (tid < 48) sB2[tid] = (tid < H2n) ? b2[tid] : 0.0f;
  __syncthreads();

  // ---------------- P1: L1 = K @ Wb (MFMA 16x16x32 f16) ----------------
  float accH[4][5][4];
  {
    f16x8 bf[5][2];
    #pragma unroll
    for (int n = 0; n < 5; ++n) {
      int c = n * 16 + l15;
      bf[n][0] = *(const f16x8*)&sWbT[c * SWB_W + l4 * 8];
      bf[n][1] = *(const f16x8*)&sWbT[c * SWB_W + 32 + l4 * 8];
    }
    #pragma unroll
    for (int s = 0; s < 4; ++s) {
      int mt = wid + s * 4;
      if (mt < MT) {
        int r = mt * 16 + l15;
        f16x8 a0 = *(const f16x8*)&sK[r * SK_W + l4 * 8];
        f16x8 a1 = *(const f16x8*)&sK[r * SK_W + 32 + l4 * 8];
        #pragma unroll
        for (int n = 0; n < 5; ++n) {
          f32x4 acc = {0.f, 0.f, 0.f, 0.f};
          acc = __builtin_amdgcn_mfma_f32_16x16x32_f16(a0, bf[n][0], acc, 0, 0, 0);
          acc = __builtin_amdgcn_mfma_f32_16x16x32_f16(a1, bf[n][1], acc, 0, 0, 0);
          accH[s][n][0] = acc[0]; accH[s][n][1] = acc[1];
          accH[s][n][2] = acc[2]; accH[s][n][3] = acc[3];
        }
      }
    }
  }
  __syncthreads();   // all waves done reading sWbT before sH overlays sU

  // ---------------- P1b: sH = sigmoid(accH + qh) (own rows -> no barrier after) --------
  #pragma unroll
  for (int s = 0; s < 4; ++s) {
    int mt = wid + s * 4;
    if (mt < MT) {
      #pragma unroll
      for (int n = 0; n < 5; ++n) {
        int c = n * 16 + l15;
        float qv = qh[c];
        #pragma unroll
        for (int i = 0; i < 4; ++i) {
          int r = mt * 16 + l4 * 4 + i;
          sH[r * SH_W + c] = (f16)fsig(accH[s][n][i] + qv);
        }
      }
    }
  }

  // ---------------- P2: L2 = H @ W2 (MFMA 16x16x16f16, K=80 in 5 ksteps) -------------
  float accG[4][3][4];
  {
    f16x4 b2f[3][5];
    #pragma unroll
    for (int n = 0; n < 3; ++n) {
      int c = n * 16 + l15;
      #pragma unroll
      for (int ks = 0; ks < 5; ++ks)
        b2f[n][ks] = *(const f16x4*)&sW2T[c * SW2_W + ks * 16 + l4 * 4];
    }
    #pragma unroll
    for (int s = 0; s < 4; ++s) {
      int mt = wid + s * 4;
      if (mt < MT) {
        int r = mt * 16 + l15;
        f16x4 af[5];
        #pragma unroll
        for (int ks = 0; ks < 5; ++ks)
          af[ks] = *(const f16x4*)&sH[r * SH_W + ks * 16 + l4 * 4];
        #pragma unroll
        for (int n = 0; n < 3; ++n) {
          f32x4 acc = {0.f, 0.f, 0.f, 0.f};
          #pragma unroll
          for (int ks = 0; ks < 5; ++ks)
            acc = __builtin_amdgcn_mfma_f32_16x16x16f16(af[ks], b2f[n][ks], acc, 0, 0, 0);
          accG[s][n][0] = acc[0]; accG[s][n][1] = acc[1];
          accG[s][n][2] = acc[2]; accG[s][n][3] = acc[3];
        }
      }
    }
  }
  __syncthreads();   // all waves done reading sH before sG overlays sU

  // ---------------- P2b: sG = sigmoid(accG + b2); then L3 on own rows ------------------
  #pragma unroll
  for (int s = 0; s < 4; ++s) {
    int mt = wid + s * 4;
    if (mt < MT) {
      #pragma unroll
      for (int n = 0; n < 3; ++n) {
        int c = n * 16 + l15;
        float bb = sB2[c];
        #pragma unroll
        for (int i = 0; i < 4; ++i) {
          int r = mt * 16 + l4 * 4 + i;
          sG[r * SG_W + c] = (f16)fsig(accG[s][n][i] + bb);
        }
      }
    }
  }

  // ---------------- P3: scores = G @ W3 + b3, mask, -> sS ------------------------------
  {
    const int len = keys_length[b];
    const float b3v = b3[0];
    f16x4 w3f[3];
    #pragma unroll
    for (int ks = 0; ks < 3; ++ks)
      w3f[ks] = *(const f16x4*)&sW3T[ks * 16 + l4 * 4];   // same for all cols (bcast)
    #pragma unroll
    for (int s = 0; s < 4; ++s) {
      int mt = wid + s * 4;
      if (mt < MT) {
        int r = mt * 16 + l15;
        f32x4 acc = {0.f, 0.f, 0.f, 0.f};
        #pragma unroll
        for (int ks = 0; ks < 3; ++ks) {
          f16x4 ag = *(const f16x4*)&sG[r * SG_W + ks * 16 + l4 * 4];
          acc = __builtin_amdgcn_mfma_f32_16x16x16f16(ag, w3f[ks], acc, 0, 0, 0);
        }
        if (l15 == 0) {
          #pragma unroll
          for (int i = 0; i < 4; ++i) {
            int rr = mt * 16 + l4 * 4 + i;
            float sc = acc[i] + b3v;
            sS[rr] = (rr < len) ? sc : 0.0f;
          }
        }
      }
    }
  }
  __syncthreads();

  // ---------------- P4: pooling out[e] = sum_t sS[t] * K[t][e] -------------------------
  {
    float ps = 0.0f;
    int t0 = wid * 50;
    for (int t = t0; t < t0 + 50; ++t)
      ps += sS[t] * (float)sK[t * SK_W + lane];
    sPool[wid][lane] = ps;
  }
  __syncthreads();
  if (tid < En)
    out[(size_t)b * En + tid] =
        sPool[0][tid] + sPool[1][tid] + sPool[2][tid] + sPool[3][tid];
}

extern "C" void kernel_launch(void* const* d_in, const int* in_sizes, int n_in,
                              void* d_out, int out_size, void* d_ws, size_t ws_size,
                              hipStream_t stream) {
  const float* query       = (const float*)d_in[0];
  const float* keys        = (const float*)d_in[1];
  const int*   keys_length = (const int*)d_in[2];
  const float* W1 = (const float*)d_in[3];
  const float* b1 = (const float*)d_in[4];
  const float* W2 = (const float*)d_in[5];
  const float* b2 = (const float*)d_in[6];
  const float* W3 = (const float*)d_in[7];
  const float* b3 = (const float*)d_in[8];
  float* out = (float*)d_out;

  hipLaunchKernelGGL(din_attn_mfma, dim3(Bn), dim3(256), 0, stream,
                     query, keys, keys_length, W1, b1, W2, b2, W3, b3, out);
}

// Round 4
// 87.993 us; speedup vs baseline: 2.4750x; 1.4875x over previous
//
#include <hip/hip_runtime.h>

// DIN attention pooling, MFMA f16, one block per batch b.
// Round-4 structure: per-wave transpose slabs (no full sH/sG), 54KB LDS -> 3 blocks/CU,
// barrier-free L1->L2->L3 midsection, prep kernel folds W1 transposes into d_ws.
//
//   Wb[e][h] = (W1b - W1c)[e][h] + q_e * W1d[e][h]
//   qh[h]    = b1[h] + sum_e q_e * (W1a + W1c)[e][h]
//   H = sigmoid(K @ Wb + qh); G = sigmoid(H @ W2 + b2); s = G @ W3 + b3 (masked)
//   out = s^T @ K

constexpr int Bn = 2048, Tn = 200, En = 64, H1n = 80, H2n = 40;
constexpr int TP = 208, MT = 13;

typedef _Float16 f16;
typedef _Float16 f16x4 __attribute__((ext_vector_type(4)));
typedef _Float16 f16x8 __attribute__((ext_vector_type(8)));
typedef float f32x4 __attribute__((ext_vector_type(4)));

constexpr int SK_W   = 72;   // keys^- row stride (144B = 9 quads, odd -> conflict-free b128)
constexpr int SWB_W  = 72;   // WbT row stride
constexpr int HS_W   = 88;   // per-wave H slab stride (176B = 11 quads)
constexpr int GS_W   = 56;   // per-wave G slab stride (112B = 7 quads)
constexpr int SW2T_W = 104;  // W2T row stride (208B = 13 quads)
constexpr int WAVE_SLAB = 16 * HS_W;  // 1408 f16 = 2816 B per wave

__device__ __forceinline__ float fsig(float x) {
  return __fdividef(1.0f, 1.0f + __expf(-x));
}

// ---- prep: fold W1 into (Wk,Wqk) pairs [80][64] and WsumT [64][80] (all f32) ----
__global__ __launch_bounds__(256) void din_prep(
    const float* __restrict__ W1, float2* __restrict__ wkq, float* __restrict__ wsumT)
{
  int idx = blockIdx.x * 256 + threadIdx.x;   // grid 20 -> 5120
  {
    int h = idx >> 6, e = idx & 63;
    float a = W1[(64 + e) * H1n + h];
    float c = W1[(128 + e) * H1n + h];
    float d = W1[(192 + e) * H1n + h];
    wkq[idx] = make_float2(a - c, d);         // [h][e] layout
  }
  {
    int e = idx / 80, h = idx - (idx / 80) * 80;  // [e][h] layout
    wsumT[idx] = W1[e * H1n + h] + W1[(128 + e) * H1n + h];
  }
}

template <bool PREP>
__global__ __launch_bounds__(256, 3) void din_main(
    const float* __restrict__ query,
    const float* __restrict__ keys,
    const int*   __restrict__ keys_length,
    const float* __restrict__ W1, const float* __restrict__ b1,
    const float* __restrict__ W2, const float* __restrict__ b2,
    const float* __restrict__ W3, const float* __restrict__ b3,
    const float2* __restrict__ wkq, const float* __restrict__ wsumT,
    float* __restrict__ out)
{
  __shared__ __align__(16) f16 sK[TP * SK_W];       // 29,952 B
  __shared__ __align__(16) f16 sU[5760];            // 11,520 B: WbT [80][72], then 4 wave slabs
  __shared__ __align__(16) f16 sW2T[48 * SW2T_W];   //  9,984 B ([j][h], h padded to 96, zeros >=80)
  __shared__ __align__(16) f16 sW3T[64];            //    128 B (zeros >=40)
  __shared__ float qh[H1n];                         //    320 B
  __shared__ float sB2[48];                         //    192 B
  __shared__ float sS[TP];                          //    832 B
  __shared__ float sTmp[256];                       //  1,024 B (pool partials)
  // total 53,952 B -> 3 blocks/CU

  const int b = blockIdx.x;
  const int tid = threadIdx.x;
  const int lane = tid & 63;
  const int wid = tid >> 6;
  const int l15 = lane & 15;
  const int l4  = lane >> 4;

  const float* qptr = query + (size_t)b * En;

  // ---------------- P0: staging ----------------
  {
    const float4* k4 = (const float4*)(keys + (size_t)b * Tn * En);
    for (int i = tid; i < Tn * En / 4; i += 256) {
      float4 v = k4[i];
      int t = i >> 4, e4 = (i & 15) << 2;
      f16x4 h = { (f16)v.x, (f16)v.y, (f16)v.z, (f16)v.w };
      *(f16x4*)&sK[t * SK_W + e4] = h;
    }
    for (int i = tid; i < 8 * 16; i += 256) {   // zero pad rows 200..207
      int t = Tn + (i >> 4), e4 = (i & 15) << 2;
      *(f16x4*)&sK[t * SK_W + e4] = (f16x4){0, 0, 0, 0};
    }
  }
  // WbT[h][e] = wk + q_e * wqk   (coalesced float2 from prep, or W1 fallback)
  for (int i = tid; i < En * H1n; i += 256) {
    int h = i >> 6, e = i & 63;
    float w;
    if (PREP) {
      float2 kq = wkq[i];
      w = kq.x + qptr[e] * kq.y;
    } else {
      w = W1[(64 + e) * H1n + h] - W1[(128 + e) * H1n + h]
        + qptr[e] * W1[(192 + e) * H1n + h];
    }
    sU[h * SWB_W + e] = (f16)w;
  }
  // W2T[j][h], cols h in [0,96), zeros for h>=80 or j>=40
  for (int i = tid; i < 48 * 24; i += 256) {
    int j = i % 48, hq = (i / 48) * 4;
    f16x4 w;
    #pragma unroll
    for (int r = 0; r < 4; ++r) {
      int h = hq + r;
      w[r] = (h < H1n && j < H2n) ? (f16)W2[h * H2n + j] : (f16)0.0f;
    }
    *(f16x4*)&sW2T[j * SW2T_W + hq] = w;
  }
  if (tid < 64) sW3T[tid] = (tid < H2n) ? (f16)W3[tid] : (f16)0.0f;
  if (tid < 48) sB2[tid] = (tid < H2n) ? b2[tid] : 0.0f;
  if (tid < H1n) {
    float a = b1[tid];
    if (PREP) {
      #pragma unroll 8
      for (int e = 0; e < En; ++e) a += qptr[e] * wsumT[e * H1n + tid];
    } else {
      #pragma unroll 8
      for (int e = 0; e < En; ++e)
        a += qptr[e] * (W1[e * H1n + tid] + W1[(128 + e) * H1n + tid]);
    }
    qh[tid] = a;
  }
  __syncthreads();

  // ---------------- load L1 B-frags, then free sWbT region for slabs ----------------
  f16x8 bf0[5], bf1[5];
  #pragma unroll
  for (int n = 0; n < 5; ++n) {
    int c = n * 16 + l15;
    bf0[n] = *(const f16x8*)&sU[c * SWB_W + l4 * 8];
    bf1[n] = *(const f16x8*)&sU[c * SWB_W + 32 + l4 * 8];
  }
  const int len = keys_length[b];
  const float b3v = b3[0];
  __syncthreads();   // all waves hold bf; sU becomes per-wave slab scratch

  f16* slab = sU + wid * WAVE_SLAB;

  // ---------------- barrier-free midsection: per wave, per 16-row tile ----------------
  for (int s = 0; s < 4; ++s) {
    int mt = wid + s * 4;
    if (mt >= MT) break;                     // wave-uniform
    int r = mt * 16 + l15;

    // L1: accH = K_tile @ Wb  (K=64 in 2 steps)
    f16x8 a0 = *(const f16x8*)&sK[r * SK_W + l4 * 8];
    f16x8 a1 = *(const f16x8*)&sK[r * SK_W + 32 + l4 * 8];
    float accH[5][4];
    #pragma unroll
    for (int n = 0; n < 5; ++n) {
      f32x4 acc = {0.f, 0.f, 0.f, 0.f};
      acc = __builtin_amdgcn_mfma_f32_16x16x32_f16(a0, bf0[n], acc, 0, 0, 0);
      acc = __builtin_amdgcn_mfma_f32_16x16x32_f16(a1, bf1[n], acc, 0, 0, 0);
      #pragma unroll
      for (int i = 0; i < 4; ++i) accH[n][i] = acc[i];
    }
    // sigmoid -> per-wave H slab [16][HS_W] (transpose C-layout -> A-layout via LDS)
    #pragma unroll
    for (int n = 0; n < 5; ++n) {
      int c = n * 16 + l15;
      float qv = qh[c];
      #pragma unroll
      for (int i = 0; i < 4; ++i)
        slab[(l4 * 4 + i) * HS_W + c] = (f16)fsig(accH[n][i] + qv);
    }

    // L2: accG = H_tile @ W2  (K=80 padded to 96, 3 steps; sW2T cols >=80 are zero)
    float accG[3][4];
    {
      f16x8 aH[3];
      #pragma unroll
      for (int ks = 0; ks < 3; ++ks)
        aH[ks] = *(const f16x8*)&slab[l15 * HS_W + ks * 32 + l4 * 8];
      #pragma unroll
      for (int n = 0; n < 3; ++n) {
        int c = n * 16 + l15;
        f32x4 acc = {0.f, 0.f, 0.f, 0.f};
        #pragma unroll
        for (int ks = 0; ks < 3; ++ks) {
          f16x8 bw = *(const f16x8*)&sW2T[c * SW2T_W + ks * 32 + l4 * 8];
          acc = __builtin_amdgcn_mfma_f32_16x16x32_f16(aH[ks], bw, acc, 0, 0, 0);
        }
        #pragma unroll
        for (int i = 0; i < 4; ++i) accG[n][i] = acc[i];
      }
    }
    // sigmoid -> per-wave G slab [16][GS_W] (reuses same slab region; same-wave LDS order)
    #pragma unroll
    for (int n = 0; n < 3; ++n) {
      int c = n * 16 + l15;
      float bb = sB2[c];
      #pragma unroll
      for (int i = 0; i < 4; ++i)
        slab[(l4 * 4 + i) * GS_W + c] = (f16)fsig(accG[n][i] + bb);
    }

    // L3: scores = G_tile @ W3 (K=48 padded to 64, 2 steps; sW3T zeros >=40)
    {
      f32x4 acc = {0.f, 0.f, 0.f, 0.f};
      #pragma unroll
      for (int ks = 0; ks < 2; ++ks) {
        f16x8 aG = *(const f16x8*)&slab[l15 * GS_W + ks * 32 + l4 * 8];
        f16x8 bw = *(const f16x8*)&sW3T[ks * 32 + l4 * 8];
        acc = __builtin_amdgcn_mfma_f32_16x16x32_f16(aG, bw, acc, 0, 0, 0);
      }
      if (l15 == 0) {
        #pragma unroll
        for (int i = 0; i < 4; ++i) {
          int rr = mt * 16 + l4 * 4 + i;
          sS[rr] = (rr < len) ? acc[i] + b3v : 0.0f;
        }
      }
    }
  }
  __syncthreads();

  // ---------------- P4: pooling out[e] = sum_t sS[t] * K[t][e] ----------------
  {
    float ps = 0.0f;
    int t0 = wid * 50;
    for (int t = t0; t < t0 + 50; ++t)
      ps += sS[t] * (float)sK[t * SK_W + lane];
    sTmp[wid * 64 + lane] = ps;
  }
  __syncthreads();
  if (tid < En)
    out[(size_t)b * En + tid] =
        sTmp[tid] + sTmp[64 + tid] + sTmp[128 + tid] + sTmp[192 + tid];
}

extern "C" void kernel_launch(void* const* d_in, const int* in_sizes, int n_in,
                              void* d_out, int out_size, void* d_ws, size_t ws_size,
                              hipStream_t stream) {
  const float* query       = (const float*)d_in[0];
  const float* keys        = (const float*)d_in[1];
  const int*   keys_length = (const int*)d_in[2];
  const float* W1 = (const float*)d_in[3];
  const float* b1 = (const float*)d_in[4];
  const float* W2 = (const float*)d_in[5];
  const float* b2 = (const float*)d_in[6];
  const float* W3 = (const float*)d_in[7];
  const float* b3 = (const float*)d_in[8];
  float* out = (float*)d_out;

  float2* wkq   = (float2*)d_ws;                       // 40,960 B
  float*  wsumT = (float*)((char*)d_ws + 40960);       // 20,480 B

  if (ws_size >= 61440) {
    hipLaunchKernelGGL(din_prep, dim3(20), dim3(256), 0, stream, W1, wkq, wsumT);
    hipLaunchKernelGGL((din_main<true>), dim3(Bn), dim3(256), 0, stream,
                       query, keys, keys_length, W1, b1, W2, b2, W3, b3, wkq, wsumT, out);
  } else {
    hipLaunchKernelGGL((din_main<false>), dim3(Bn), dim3(256), 0, stream,
                       query, keys, keys_length, W1, b1, W2, b2, W3, b3, wkq, wsumT, out);
  }
}